// Round 1
// baseline (1542.540 us; speedup 1.0000x reference)
//
#include <hip/hip_runtime.h>

#define NROWS 262144
#define KCOLS 512
// 4 waves per block, one wave (64 lanes) per row; each lane owns 8 elements.

__global__ __launch_bounds__(256) void sce_rows(const float* __restrict__ x,
                                                const float* __restrict__ t,
                                                const float* __restrict__ w,
                                                double* __restrict__ partial) {
    const int wave = threadIdx.x >> 6;
    const int lane = threadIdx.x & 63;
    const long long row = (long long)blockIdx.x * 4 + wave;

    const float* __restrict__ xr = x + row * KCOLS;
    const float* __restrict__ tr = t + row * KCOLS;

    const int o0 = lane * 4;        // chunk 0: elements [0,256)
    const int o1 = 256 + lane * 4;  // chunk 1: elements [256,512)

    const float4 x0 = *(const float4*)(xr + o0);
    const float4 x1 = *(const float4*)(xr + o1);
    const float4 t0 = *(const float4*)(tr + o0);
    const float4 t1 = *(const float4*)(tr + o1);
    const float4 w0 = *(const float4*)(w + o0);
    const float4 w1 = *(const float4*)(w + o1);

    // 1) row max
    float m = fmaxf(fmaxf(fmaxf(x0.x, x0.y), fmaxf(x0.z, x0.w)),
                    fmaxf(fmaxf(x1.x, x1.y), fmaxf(x1.z, x1.w)));
    #pragma unroll
    for (int off = 32; off > 0; off >>= 1)
        m = fmaxf(m, __shfl_xor(m, off, 64));

    // 2) sum exp(x - m)
    float se = __expf(x0.x - m) + __expf(x0.y - m) + __expf(x0.z - m) + __expf(x0.w - m)
             + __expf(x1.x - m) + __expf(x1.y - m) + __expf(x1.z - m) + __expf(x1.w - m);
    #pragma unroll
    for (int off = 32; off > 0; off >>= 1)
        se += __shfl_xor(se, off, 64);

    const float lse = m + __logf(se);

    // 3) per_row = sum t*w*(lse - x)   (== -sum t*w*logp)
    float acc = t0.x * w0.x * (lse - x0.x) + t0.y * w0.y * (lse - x0.y)
              + t0.z * w0.z * (lse - x0.z) + t0.w * w0.w * (lse - x0.w)
              + t1.x * w1.x * (lse - x1.x) + t1.y * w1.y * (lse - x1.y)
              + t1.z * w1.z * (lse - x1.z) + t1.w * w1.w * (lse - x1.w);
    #pragma unroll
    for (int off = 32; off > 0; off >>= 1)
        acc += __shfl_xor(acc, off, 64);

    __shared__ float wsum[4];
    if (lane == 0) wsum[wave] = acc;
    __syncthreads();
    if (threadIdx.x == 0) {
        float s = wsum[0] + wsum[1] + wsum[2] + wsum[3];
        atomicAdd(partial, (double)s);
    }
}

__global__ void sce_finalize(const double* __restrict__ partial, float* __restrict__ out) {
    out[0] = (float)(partial[0] / (double)NROWS);
}

extern "C" void kernel_launch(void* const* d_in, const int* in_sizes, int n_in,
                              void* d_out, int out_size, void* d_ws, size_t ws_size,
                              hipStream_t stream) {
    const float* x = (const float*)d_in[0];
    const float* t = (const float*)d_in[1];
    const float* w = (const float*)d_in[2];
    float* out = (float*)d_out;
    double* partial = (double*)d_ws;

    hipMemsetAsync(partial, 0, sizeof(double), stream);
    sce_rows<<<NROWS / 4, 256, 0, stream>>>(x, t, w, partial);
    sce_finalize<<<1, 1, 0, stream>>>(partial, out);
}